// Round 5
// baseline (259.527 us; speedup 1.0000x reference)
//
#include <hip/hip_runtime.h>
#include <math.h>

#define BATCH 64
#define ADIM  1152
#define BDIM  32
#define POSE  16
#define SLICE 512                 // BDIM*POSE floats per (bt, a) row
#define CHUNKS 16
#define ROWS  72                  // rows per block = ADIM/CHUNKS
#define RPW   18                  // rows per wave (4 waves/block)
#define EPSQ  1e-6f
#define SPART_ITER ((size_t)BATCH * CHUNKS * SLICE)

typedef float v4f __attribute__((ext_vector_type(4)));

// pack two floats -> bf16x2 (round-to-nearest-even)
__device__ __forceinline__ unsigned pack_bf16x2(float a, float b) {
    unsigned ua = __float_as_uint(a), ub = __float_as_uint(b);
    ua = (ua + 0x7fffu + ((ua >> 16) & 1u)) >> 16;
    ub = (ub + 0x7fffu + ((ub >> 16) & 1u));
    return (ua & 0xffffu) | (ub & 0xffff0000u);
}

__device__ __forceinline__ v4f unpack_bf16x4(unsigned lo, unsigned hi) {
    v4f r;
    r.x = __uint_as_float(lo << 16);
    r.y = __uint_as_float(lo & 0xffff0000u);
    r.z = __uint_as_float(hi << 16);
    r.w = __uint_as_float(hi & 0xffff0000u);
    return r;
}

// ---------------------------------------------------------------------------
// s_part layout (unchanged): [iter][bt][chunk][512 floats]; v4f slot s holds
// capsule b = s>>2, poses 4*(s&3)..4*(s&3)+3.
// Pair mapping (iter kernels only): lane l owns slots 2l and 2l+1 -> both
// capsule b = l>>1; with q = l&1, slot 2l covers poses 8q..8q+3 and slot
// 2l+1 covers poses 8q+4..8q+7. Lane pair (2m, 2m+1) = capsule m.
// ---------------------------------------------------------------------------

// squash under the pair mapping: reduce chunk partials, then n[pose] via
// parity-class reduction (xor 2..32 sums over the 32 lanes of one parity,
// which hold each capsule exactly once).
__device__ __forceinline__ void squash_pair(const float* sp, int lane,
                                            v4f& sA, v4f& sB,
                                            v4f& facA, v4f& facB) {
    const v4f* spv = (const v4f*)sp;
    sA = (v4f){0.f, 0.f, 0.f, 0.f};
    sB = (v4f){0.f, 0.f, 0.f, 0.f};
#pragma unroll
    for (int c = 0; c < CHUNKS; ++c) {
        sA += spv[c * 128 + 2 * lane];
        sB += spv[c * 128 + 2 * lane + 1];
    }
    v4f nA = sA * sA;
    v4f nB = sB * sB;
#pragma unroll
    for (int off = 2; off <= 32; off <<= 1) {
        nA.x += __shfl_xor(nA.x, off, 64); nA.y += __shfl_xor(nA.y, off, 64);
        nA.z += __shfl_xor(nA.z, off, 64); nA.w += __shfl_xor(nA.w, off, 64);
        nB.x += __shfl_xor(nB.x, off, 64); nB.y += __shfl_xor(nB.y, off, 64);
        nB.z += __shfl_xor(nB.z, off, 64); nB.w += __shfl_xor(nB.w, off, 64);
    }
    facA.x = sqrtf(nA.x + EPSQ) / (1.f + nA.x);
    facA.y = sqrtf(nA.y + EPSQ) / (1.f + nA.y);
    facA.z = sqrtf(nA.z + EPSQ) / (1.f + nA.z);
    facA.w = sqrtf(nA.w + EPSQ) / (1.f + nA.w);
    facB.x = sqrtf(nB.x + EPSQ) / (1.f + nB.x);
    facB.y = sqrtf(nB.y + EPSQ) / (1.f + nB.y);
    facB.z = sqrtf(nB.z + EPSQ) / (1.f + nB.z);
    facB.w = sqrtf(nB.w + EPSQ) / (1.f + nB.w);
}

// ---------------------------------------------------------------------------
// Pass 0 (unchanged, proven): stream fp32 v once (nontemporal), write bf16
// tile (cached -> L3-resident for iters), accumulate s0 = sum_a c0*v from
// full-precision data in the same loop.
// ---------------------------------------------------------------------------
__global__ __launch_bounds__(256) void route0_compress(
    const float* __restrict__ v,       // [BATCH][ADIM][BDIM][POSE]
    const float* __restrict__ logits,  // [ADIM][BDIM]
    uint2* __restrict__ tile,          // bf16 copy of v, same layout
    float* __restrict__ s_part)        // [BATCH][CHUNKS][SLICE]
{
    const int bt    = blockIdx.x >> 4;
    const int chunk = blockIdx.x & 15;
    const int t     = threadIdx.x;
    const int bc0   = (t >> 2) & 31;
    const int hi    = t >> 7;
    const int a0    = chunk * ROWS;

    __shared__ float w_sh[ROWS * BDIM];   // 9 KB
    __shared__ v4f   red[128];            // 2 KB

    if (t < ROWS) {
        const float* lr = logits + (size_t)(a0 + t) * BDIM;
        float s = 0.f;
        float e[BDIM];
#pragma unroll
        for (int b = 0; b < BDIM; ++b) { e[b] = __expf(lr[b]); s += e[b]; }
        float rd = 1.f / s;
#pragma unroll
        for (int b = 0; b < BDIM; ++b) w_sh[t * BDIM + b] = e[b] * rd;
    }
    __syncthreads();

    const v4f* vg = (const v4f*)(v + ((size_t)bt * ADIM + a0) * SLICE);
    uint2*     tg = tile + ((size_t)bt * ADIM + a0) * 128;

    v4f acc = (v4f){0.f, 0.f, 0.f, 0.f};
    v4f fA[6], fB[6];
#pragma unroll
    for (int u = 0; u < 6; ++u)
        fA[u] = __builtin_nontemporal_load(&vg[t + 256 * u]);

#pragma unroll
    for (int kk = 0; kk < 6; ++kk) {
        v4f* cur = (kk & 1) ? fB : fA;
        v4f* nxt = (kk & 1) ? fA : fB;
        if (kk + 1 < 6) {
#pragma unroll
            for (int u = 0; u < 6; ++u)
                nxt[u] = __builtin_nontemporal_load(&vg[t + 256 * ((kk + 1) * 6 + u)]);
        }
#pragma unroll
        for (int u = 0; u < 6; ++u) {
            const int k   = kk * 6 + u;
            const int i   = t + 256 * k;
            const int row = 2 * k + hi;
            tg[i] = make_uint2(pack_bf16x2(cur[u].x, cur[u].y),
                               pack_bf16x2(cur[u].z, cur[u].w));
            float c0 = w_sh[row * BDIM + bc0];
            acc += c0 * cur[u];
        }
    }

    __syncthreads();
    if (t >= 128) red[t - 128] = acc;
    __syncthreads();
    if (t < 128) {
        acc += red[t];
        ((v4f*)(s_part + ((size_t)bt * CHUNKS + chunk) * SLICE))[t] = acc;
    }
}

// ---------------------------------------------------------------------------
// Iteration pass (iters 1 and 2), pair mapping. One uint4 load per row per
// lane (16B coalesced: row*64 + lane), 3-group-deep prefetch (144 B/lane in
// flight), 1 exp + 6 shfl per row. Logits staged in LDS. psum recomputed
// per block from L2-resident s_part (bitwise-identical everywhere).
// ---------------------------------------------------------------------------
__global__ __launch_bounds__(256) void iter_tile(
    const uint4* __restrict__ tile,    // [bt][a][64 uint4] (same bytes as route0's tile)
    const float* __restrict__ logits,
    const float* __restrict__ s_part,  // [3][BATCH][CHUNKS][SLICE]
    float* __restrict__ s_next,        // [BATCH][CHUNKS][SLICE]
    int nprev)
{
    const int bt    = blockIdx.x >> 4;
    const int chunk = blockIdx.x & 15;
    const int t     = threadIdx.x;
    const int lane  = t & 63;
    const int wv    = t >> 6;
    const int bb    = lane >> 1;       // capsule of this lane
    const int a0    = chunk * ROWS;
    const int r0    = wv * RPW;

    __shared__ float lg_sh[ROWS * BDIM];  // 9 KB
    __shared__ v4f   red[128];            // 2 KB

    for (int i = t; i < ROWS * BDIM; i += 256)
        lg_sh[i] = logits[(size_t)a0 * BDIM + i];
    __syncthreads();

    v4f pA = (v4f){0.f, 0.f, 0.f, 0.f};
    v4f pB = (v4f){0.f, 0.f, 0.f, 0.f};
    for (int j = 0; j < nprev; ++j) {
        v4f sA, sB, fA_, fB_;
        squash_pair(s_part + (size_t)j * SPART_ITER +
                    (size_t)bt * CHUNKS * SLICE, lane, sA, sB, fA_, fB_);
        pA += fA_ * sA;
        pB += fB_ * sB;
    }

    const uint4* tb = tile + ((size_t)bt * ADIM + a0 + r0) * 64;

    v4f acc0 = (v4f){0.f, 0.f, 0.f, 0.f};
    v4f acc1 = (v4f){0.f, 0.f, 0.f, 0.f};
    uint4 bufA[3], bufB[3], bufC[3];

#define PREFETCH(DST, G)                                                  \
    {                                                                     \
        _Pragma("unroll")                                                 \
        for (int u = 0; u < 3; ++u)                                       \
            DST[u] = tb[((G) * 3 + u) * 64 + lane];                       \
    }

#define COMPUTE(SRC, G)                                                   \
    {                                                                     \
        _Pragma("unroll")                                                 \
        for (int i = 0; i < 3; ++i) {                                     \
            const int rw = r0 + (G) * 3 + i;                              \
            v4f va = unpack_bf16x4(SRC[i].x, SRC[i].y);                   \
            v4f vb = unpack_bf16x4(SRC[i].z, SRC[i].w);                   \
            float d = pA.x * va.x + pA.y * va.y + pA.z * va.z             \
                    + pA.w * va.w + pB.x * vb.x + pB.y * vb.y             \
                    + pB.z * vb.z + pB.w * vb.w;                          \
            d += __shfl_xor(d, 1, 64);                                    \
            float e = __expf(lg_sh[rw * BDIM + bb] + d);                  \
            float uu = e;                                                 \
            uu += __shfl_xor(uu, 2, 64);                                  \
            uu += __shfl_xor(uu, 4, 64);                                  \
            uu += __shfl_xor(uu, 8, 64);                                  \
            uu += __shfl_xor(uu, 16, 64);                                 \
            uu += __shfl_xor(uu, 32, 64);                                 \
            float cc = e * __builtin_amdgcn_rcpf(uu);                     \
            acc0 += cc * va;                                              \
            acc1 += cc * vb;                                              \
        }                                                                 \
    }

    PREFETCH(bufA, 0)
    PREFETCH(bufB, 1)
    PREFETCH(bufC, 2)
    COMPUTE(bufA, 0)
    PREFETCH(bufA, 3)
    COMPUTE(bufB, 1)
    PREFETCH(bufB, 4)
    COMPUTE(bufC, 2)
    PREFETCH(bufC, 5)
    COMPUTE(bufA, 3)
    COMPUTE(bufB, 4)
    COMPUTE(bufC, 5)

#undef PREFETCH
#undef COMPUTE

    // cross-wave reduce; lane owns v4f slots 2l, 2l+1 (32B contiguous)
    __syncthreads();
    if (wv == 3) { red[2 * lane] = acc0; red[2 * lane + 1] = acc1; }
    __syncthreads();
    if (wv == 2) { red[2 * lane] += acc0; red[2 * lane + 1] += acc1; }
    __syncthreads();
    if (wv == 1) { red[2 * lane] += acc0; red[2 * lane + 1] += acc1; }
    __syncthreads();
    if (wv == 0) {
        v4f* sp = (v4f*)(s_next + ((size_t)bt * CHUNKS + chunk) * SLICE);
        sp[2 * lane]     = red[2 * lane] + acc0;
        sp[2 * lane + 1] = red[2 * lane + 1] + acc1;
    }
}

// final: reduce iter-2 chunk partials, squash, emit a_out (8192) ++ p (32768)
__global__ __launch_bounds__(512) void final_out(
    const float* __restrict__ s_part2,  // [bt][CHUNKS][SLICE]
    float* __restrict__ out)
{
    const int bt = blockIdx.x;
    const int t  = threadIdx.x;        // t = b*16 + pose
    const int pose = t & 15;

    __shared__ float sq[SLICE];
    __shared__ float ns[POSE];

    float sv = 0.f;
#pragma unroll
    for (int c = 0; c < CHUNKS; ++c)
        sv += s_part2[((size_t)bt * CHUNKS + c) * SLICE + t];

    sq[t] = sv * sv;
    __syncthreads();
    if (t < POSE) {
        float a = 0.f;
        for (int b2 = 0; b2 < BDIM; ++b2) a += sq[b2 * POSE + t];
        ns[t] = a;
    }
    __syncthreads();
    float n = ns[pose];
    float pv = sqrtf(n + EPSQ) / (1.f + n) * sv;

    out[8192 + (size_t)bt * SLICE + t] = pv;
    sq[t] = pv * pv;
    __syncthreads();
    // a_out[bt][b2][p2] = sqrt(sum_p1 p[b2][p1*4+p2]^2)
    if (t < 128) {
        const int b2 = t >> 2, p2 = t & 3;
        float a = 0.f;
#pragma unroll
        for (int p1 = 0; p1 < 4; ++p1) a += sq[b2 * POSE + p1 * 4 + p2];
        out[(size_t)bt * 128 + t] = sqrtf(a);
    }
}

extern "C" void kernel_launch(void* const* d_in, const int* in_sizes, int n_in,
                              void* d_out, int out_size, void* d_ws, size_t ws_size,
                              hipStream_t stream) {
    const float* v      = (const float*)d_in[1];   // (64,1152,32,4,4,1)
    const float* logits = (const float*)d_in[2];   // (1,1152,32,1,1,1)
    float* out = (float*)d_out;

    // ws: bf16 tile (75.5 MB) ++ s_part[3][BATCH][CHUNKS][SLICE] (6 MB).
    // All regions written before read -> no memset needed.
    uint2* tile   = (uint2*)d_ws;
    float* s_part = (float*)((char*)d_ws + (size_t)BATCH * ADIM * 128 * sizeof(uint2));

    route0_compress<<<dim3(BATCH * CHUNKS), dim3(256), 0, stream>>>(
        v, logits, tile, s_part + 0 * SPART_ITER);
    iter_tile<<<dim3(BATCH * CHUNKS), dim3(256), 0, stream>>>(
        (const uint4*)tile, logits, s_part, s_part + 1 * SPART_ITER, 1);
    iter_tile<<<dim3(BATCH * CHUNKS), dim3(256), 0, stream>>>(
        (const uint4*)tile, logits, s_part, s_part + 2 * SPART_ITER, 2);
    final_out<<<dim3(BATCH), dim3(512), 0, stream>>>(
        s_part + 2 * SPART_ITER, out);
}

// Round 6
// 254.103 us; speedup vs baseline: 1.0213x; 1.0213x over previous
//
#include <hip/hip_runtime.h>
#include <math.h>

#define BATCH 64
#define ADIM  1152
#define BDIM  32
#define POSE  16
#define SLICE 512                 // BDIM*POSE floats per (bt, a) row
#define CHUNKS 16
#define ROWS  72                  // rows per block = ADIM/CHUNKS
#define RPW   18                  // rows per wave (4 waves/block)
#define EPSQ  1e-6f
#define SPART_ITER ((size_t)BATCH * CHUNKS * SLICE)

typedef float v4f __attribute__((ext_vector_type(4)));

// pack two floats -> bf16x2 (round-to-nearest-even)
__device__ __forceinline__ unsigned pack_bf16x2(float a, float b) {
    unsigned ua = __float_as_uint(a), ub = __float_as_uint(b);
    ua = (ua + 0x7fffu + ((ua >> 16) & 1u)) >> 16;
    ub = (ub + 0x7fffu + ((ub >> 16) & 1u));
    return (ua & 0xffffu) | (ub & 0xffff0000u);
}

__device__ __forceinline__ v4f unpack_bf16x4(uint2 w) {
    v4f r;
    r.x = __uint_as_float(w.x << 16);
    r.y = __uint_as_float(w.x & 0xffff0000u);
    r.z = __uint_as_float(w.y << 16);
    r.w = __uint_as_float(w.y & 0xffff0000u);
    return r;
}

// ---------------------------------------------------------------------------
// s_part layout: [iter][bt][chunk][512 floats]; v4f slot s holds capsule
// b = s>>2, poses 4*(s&3)..4*(s&3)+3. Wave lane l owns slots l (b=l>>2) and
// 64+l (b=16+(l>>2)) -- R4's proven mapping.
// ---------------------------------------------------------------------------

// Reduce 16 chunk partials of one batch, then squash. n[pose] = sum_b s^2
// reduced over the 16 lanes sharing l&3 via xor-4..32 shuffles.
__device__ __forceinline__ void squash_from(const float* sp, int lane,
                                            v4f& sA, v4f& sB, v4f& fac) {
    const v4f* spv = (const v4f*)sp;
    sA = (v4f){0.f, 0.f, 0.f, 0.f};
    sB = (v4f){0.f, 0.f, 0.f, 0.f};
#pragma unroll
    for (int c = 0; c < CHUNKS; ++c) {
        sA += spv[c * 128 + lane];
        sB += spv[c * 128 + 64 + lane];
    }
    v4f nq = sA * sA + sB * sB;
#pragma unroll
    for (int off = 4; off <= 32; off <<= 1) {
        nq.x += __shfl_xor(nq.x, off, 64);
        nq.y += __shfl_xor(nq.y, off, 64);
        nq.z += __shfl_xor(nq.z, off, 64);
        nq.w += __shfl_xor(nq.w, off, 64);
    }
    fac.x = sqrtf(nq.x + EPSQ) / (1.f + nq.x);
    fac.y = sqrtf(nq.y + EPSQ) / (1.f + nq.y);
    fac.z = sqrtf(nq.z + EPSQ) / (1.f + nq.z);
    fac.w = sqrtf(nq.w + EPSQ) / (1.f + nq.w);
}

// cross-wave reduce of per-wave partials; wv0 writes slots lane / 64+lane
__device__ __forceinline__ void reduce_write(v4f* red, int lane, int wv,
                                             v4f ra, v4f rb, float* dst) {
    __syncthreads();
    if (wv == 3) { red[lane] = ra; red[64 + lane] = rb; }
    __syncthreads();
    if (wv == 2) { red[lane] += ra; red[64 + lane] += rb; }
    __syncthreads();
    if (wv == 1) { red[lane] += ra; red[64 + lane] += rb; }
    __syncthreads();
    if (wv == 0) {
        v4f* sp = (v4f*)dst;
        sp[lane]      = red[lane] + ra;
        sp[64 + lane] = red[64 + lane] + rb;
    }
}

// ---------------------------------------------------------------------------
// Pass 0 (unchanged, proven): stream fp32 v once (nontemporal), write bf16
// tile (cached -> L3-resident for iters), accumulate s0 = sum_a c0*v from
// full-precision data in the same loop.
// ---------------------------------------------------------------------------
__global__ __launch_bounds__(256) void route0_compress(
    const float* __restrict__ v,       // [BATCH][ADIM][BDIM][POSE]
    const float* __restrict__ logits,  // [ADIM][BDIM]
    uint2* __restrict__ tile,          // bf16 copy of v, same layout
    float* __restrict__ s_part)        // [BATCH][CHUNKS][SLICE]
{
    const int bt    = blockIdx.x >> 4;
    const int chunk = blockIdx.x & 15;
    const int t     = threadIdx.x;
    const int bc0   = (t >> 2) & 31;
    const int hi    = t >> 7;
    const int a0    = chunk * ROWS;

    __shared__ float w_sh[ROWS * BDIM];   // 9 KB
    __shared__ v4f   red[128];            // 2 KB

    if (t < ROWS) {
        const float* lr = logits + (size_t)(a0 + t) * BDIM;
        float s = 0.f;
        float e[BDIM];
#pragma unroll
        for (int b = 0; b < BDIM; ++b) { e[b] = __expf(lr[b]); s += e[b]; }
        float rd = 1.f / s;
#pragma unroll
        for (int b = 0; b < BDIM; ++b) w_sh[t * BDIM + b] = e[b] * rd;
    }
    __syncthreads();

    const v4f* vg = (const v4f*)(v + ((size_t)bt * ADIM + a0) * SLICE);
    uint2*     tg = tile + ((size_t)bt * ADIM + a0) * 128;

    v4f acc = (v4f){0.f, 0.f, 0.f, 0.f};
    v4f fA[6], fB[6];
#pragma unroll
    for (int u = 0; u < 6; ++u)
        fA[u] = __builtin_nontemporal_load(&vg[t + 256 * u]);

#pragma unroll
    for (int kk = 0; kk < 6; ++kk) {
        v4f* cur = (kk & 1) ? fB : fA;
        v4f* nxt = (kk & 1) ? fA : fB;
        if (kk + 1 < 6) {
#pragma unroll
            for (int u = 0; u < 6; ++u)
                nxt[u] = __builtin_nontemporal_load(&vg[t + 256 * ((kk + 1) * 6 + u)]);
        }
#pragma unroll
        for (int u = 0; u < 6; ++u) {
            const int k   = kk * 6 + u;
            const int i   = t + 256 * k;
            const int row = 2 * k + hi;
            tg[i] = make_uint2(pack_bf16x2(cur[u].x, cur[u].y),
                               pack_bf16x2(cur[u].z, cur[u].w));
            float c0 = w_sh[row * BDIM + bc0];
            acc += c0 * cur[u];
        }
    }

    __syncthreads();
    if (t >= 128) red[t - 128] = acc;
    __syncthreads();
    if (t < 128) {
        acc += red[t];
        ((v4f*)(s_part + ((size_t)bt * CHUNKS + chunk) * SLICE))[t] = acc;
    }
}

// ---------------------------------------------------------------------------
// Iteration pass (iters 1 and 2) from the bf16 tile. R4's mapping and math;
// the ONLY change vs R4: triple-buffered prefetch (3 row-groups = 18 uint2 =
// 144 B/lane in flight) to cover L2/L3 latency. psum = sum_{j<nprev}
// squash(s_j) recomputed per block from L2-resident s_part.
// ---------------------------------------------------------------------------
__global__ __launch_bounds__(256) void iter_tile(
    const uint2* __restrict__ tile,
    const float* __restrict__ logits,
    const float* __restrict__ s_part,  // [3][BATCH][CHUNKS][SLICE]
    float* __restrict__ s_next,        // [BATCH][CHUNKS][SLICE]
    int nprev)
{
    const int bt    = blockIdx.x >> 4;
    const int chunk = blockIdx.x & 15;
    const int t     = threadIdx.x;
    const int lane  = t & 63;
    const int wv    = t >> 6;
    const int bq    = lane >> 2;
    const int a0    = chunk * ROWS;
    const int r0    = wv * RPW;

    __shared__ v4f red[128];           // 2 KB

    v4f pA = (v4f){0.f, 0.f, 0.f, 0.f};
    v4f pB = (v4f){0.f, 0.f, 0.f, 0.f};
    for (int j = 0; j < nprev; ++j) {
        v4f sA, sB, fac;
        squash_from(s_part + (size_t)j * SPART_ITER +
                    (size_t)bt * CHUNKS * SLICE, lane, sA, sB, fac);
        pA += fac * sA;
        pB += fac * sB;
    }

    const uint2* tb  = tile + ((size_t)bt * ADIM + a0 + r0) * 128;
    const float* lgr = logits + (size_t)(a0 + r0) * BDIM;

    v4f acc0 = (v4f){0.f, 0.f, 0.f, 0.f};
    v4f acc1 = (v4f){0.f, 0.f, 0.f, 0.f};

    // group g covers rows 3g..3g+2; per row two uint2 loads (lane, 64+lane)
    uint2 bufA[6], bufB[6], bufC[6];

#define PREFETCH(DST, G)                                                   \
    {                                                                      \
        _Pragma("unroll")                                                  \
        for (int u = 0; u < 6; ++u)                                        \
            DST[u] = tb[(3 * (G) + (u >> 1)) * 128 + (u & 1) * 64 + lane]; \
    }

#define COMPUTE(SRC, G)                                                    \
    {                                                                      \
        _Pragma("unroll")                                                  \
        for (int i = 0; i < 3; ++i) {                                      \
            const int rw = 3 * (G) + i;                                    \
            v4f va = unpack_bf16x4(SRC[2 * i]);                            \
            v4f vb = unpack_bf16x4(SRC[2 * i + 1]);                        \
            float b0 = lgr[rw * BDIM + bq];                                \
            float b1 = lgr[rw * BDIM + 16 + bq];                           \
            float d0 = pA.x * va.x + pA.y * va.y + pA.z * va.z             \
                     + pA.w * va.w;                                        \
            float d1 = pB.x * vb.x + pB.y * vb.y + pB.z * vb.z             \
                     + pB.w * vb.w;                                        \
            d0 += __shfl_xor(d0, 1, 64); d0 += __shfl_xor(d0, 2, 64);      \
            d1 += __shfl_xor(d1, 1, 64); d1 += __shfl_xor(d1, 2, 64);      \
            float e0 = __expf(b0 + d0);                                    \
            float e1 = __expf(b1 + d1);                                    \
            float uu = e0 + e1;                                            \
            uu += __shfl_xor(uu, 4, 64);                                   \
            uu += __shfl_xor(uu, 8, 64);                                   \
            uu += __shfl_xor(uu, 16, 64);                                  \
            uu += __shfl_xor(uu, 32, 64);                                  \
            float rdc = __builtin_amdgcn_rcpf(uu);                         \
            acc0 += (e0 * rdc) * va;                                       \
            acc1 += (e1 * rdc) * vb;                                       \
        }                                                                  \
    }

    PREFETCH(bufA, 0)
    PREFETCH(bufB, 1)
    PREFETCH(bufC, 2)
    COMPUTE(bufA, 0)
    PREFETCH(bufA, 3)
    COMPUTE(bufB, 1)
    PREFETCH(bufB, 4)
    COMPUTE(bufC, 2)
    PREFETCH(bufC, 5)
    COMPUTE(bufA, 3)
    COMPUTE(bufB, 4)
    COMPUTE(bufC, 5)

#undef PREFETCH
#undef COMPUTE

    reduce_write(red, lane, wv, acc0, acc1,
                 s_next + ((size_t)bt * CHUNKS + chunk) * SLICE);
}

// final: reduce iter-2 chunk partials, squash, emit a_out (8192) ++ p (32768)
__global__ __launch_bounds__(512) void final_out(
    const float* __restrict__ s_part2,  // [bt][CHUNKS][SLICE]
    float* __restrict__ out)
{
    const int bt = blockIdx.x;
    const int t  = threadIdx.x;        // t = b*16 + pose
    const int pose = t & 15;

    __shared__ float sq[SLICE];
    __shared__ float ns[POSE];

    float sv = 0.f;
#pragma unroll
    for (int c = 0; c < CHUNKS; ++c)
        sv += s_part2[((size_t)bt * CHUNKS + c) * SLICE + t];

    sq[t] = sv * sv;
    __syncthreads();
    if (t < POSE) {
        float a = 0.f;
        for (int b2 = 0; b2 < BDIM; ++b2) a += sq[b2 * POSE + t];
        ns[t] = a;
    }
    __syncthreads();
    float n = ns[pose];
    float pv = sqrtf(n + EPSQ) / (1.f + n) * sv;

    out[8192 + (size_t)bt * SLICE + t] = pv;
    sq[t] = pv * pv;
    __syncthreads();
    // a_out[bt][b2][p2] = sqrt(sum_p1 p[b2][p1*4+p2]^2)
    if (t < 128) {
        const int b2 = t >> 2, p2 = t & 3;
        float a = 0.f;
#pragma unroll
        for (int p1 = 0; p1 < 4; ++p1) a += sq[b2 * POSE + p1 * 4 + p2];
        out[(size_t)bt * 128 + t] = sqrtf(a);
    }
}

extern "C" void kernel_launch(void* const* d_in, const int* in_sizes, int n_in,
                              void* d_out, int out_size, void* d_ws, size_t ws_size,
                              hipStream_t stream) {
    const float* v      = (const float*)d_in[1];   // (64,1152,32,4,4,1)
    const float* logits = (const float*)d_in[2];   // (1,1152,32,1,1,1)
    float* out = (float*)d_out;

    // ws: bf16 tile (75.5 MB) ++ s_part[3][BATCH][CHUNKS][SLICE] (6 MB).
    // All regions written before read -> no memset needed.
    uint2* tile   = (uint2*)d_ws;
    float* s_part = (float*)((char*)d_ws + (size_t)BATCH * ADIM * 128 * sizeof(uint2));

    route0_compress<<<dim3(BATCH * CHUNKS), dim3(256), 0, stream>>>(
        v, logits, tile, s_part + 0 * SPART_ITER);
    iter_tile<<<dim3(BATCH * CHUNKS), dim3(256), 0, stream>>>(
        tile, logits, s_part, s_part + 1 * SPART_ITER, 1);
    iter_tile<<<dim3(BATCH * CHUNKS), dim3(256), 0, stream>>>(
        tile, logits, s_part, s_part + 2 * SPART_ITER, 2);
    final_out<<<dim3(BATCH), dim3(512), 0, stream>>>(
        s_part + 2 * SPART_ITER, out);
}